// Round 18
// baseline (1014.358 us; speedup 1.0000x reference)
//
#include <hip/hip_runtime.h>
#include <hip/hip_bf16.h>

#define B_SZ 1024
#define H_DIM 1536
#define H3 (3*H_DIM)
#define LMAX 32
#define TEMP_INV 20.0f

typedef __attribute__((ext_vector_type(4))) float f32x4;
typedef __attribute__((ext_vector_type(8))) short short8;
typedef unsigned short u16;
typedef unsigned int u32;

__device__ __forceinline__ u16 f2bf(float f){
  union { float f; u32 u; } v; v.f = f;
  u32 r = (v.u + 0x7FFFu + ((v.u >> 16) & 1u)) >> 16;
  return (u16)r;
}
__device__ __forceinline__ u32 pack2(float lo, float hi){
  return (u32)f2bf(lo) | ((u32)f2bf(hi) << 16);
}
__device__ __forceinline__ float bf2f(u16 b){
  union { u32 u; float f; } v; v.u = ((u32)b) << 16; return v.f;
}
__device__ __forceinline__ float sigm(float x){ return 1.f / (1.f + __expf(-x)); }

__device__ __forceinline__ void gload_lds16(const void* g, void* l){
  __builtin_amdgcn_global_load_lds(
      (const __attribute__((address_space(1))) void*)g,
      (__attribute__((address_space(3))) void*)l, 16, 0, 0);
}

// ---- sort: ballot-based counting rank (desc by len, stable) ----------------
__global__ void sort_kernel(const int* __restrict__ lens, int* __restrict__ rank,
                            int* __restrict__ cnt_arr, int* __restrict__ tstart,
                            int* __restrict__ rowmap)
{
  __shared__ int wavecnt[33][17];   // [bin][wave], padded
  __shared__ int bintot[33];
  __shared__ int scnt[LMAX];
  __shared__ int sts[LMAX];
  __shared__ int soff[B_SZ];
  int i = threadIdx.x;
  int li = lens[i];
  int w = i >> 6, lane = i & 63;

  if (i < 33 * 17) ((int*)wavecnt)[i] = 0;
  __syncthreads();

  int mypre = 0;
  #pragma unroll 1
  for (int b = 0; b <= 32; ++b) {
    unsigned long long m = __ballot(li == b);
    if (lane == 0) wavecnt[b][w] = __popcll(m);
    if (b == li) mypre = __popcll(m & ((1ull << lane) - 1ull));
  }
  __syncthreads();

  if (i < 33) {
    int c = 0;
    #pragma unroll 1
    for (int w2 = 0; w2 < 16; ++w2) c += wavecnt[i][w2];
    bintot[i] = c;
  }
  __syncthreads();

  int wpre = 0;
  #pragma unroll 1
  for (int w2 = 0; w2 < w; ++w2) wpre += wavecnt[li][w2];
  int base = 0;
  #pragma unroll 1
  for (int b = li + 1; b <= 32; ++b) base += bintot[b];
  int r = base + wpre + mypre;
  rank[i] = r;

  if (i < LMAX) {
    int c = 0;
    #pragma unroll 1
    for (int b = i + 1; b <= 32; ++b) c += bintot[b];
    scnt[i] = c; cnt_arr[i] = c;
  }
  __syncthreads();
  if (i == 0) {
    int acc = 0;
    for (int t = 0; t < LMAX; ++t) { sts[t] = acc; tstart[t] = acc; acc += scnt[t]; }
  }

  soff[i] = li;
  __syncthreads();
  for (int off = 1; off < B_SZ; off <<= 1) {
    int v = (i >= off) ? soff[i - off] : 0;
    __syncthreads();
    soff[i] += v;
    __syncthreads();
  }
  int myoff = soff[i] - li;
  for (int t = 0; t < li; ++t)
    rowmap[myoff + t] = sts[t] + r;       // packed (t, rank) position
}

// ---------------- prep: weights/k -> bf16, hs0[rank[i]] = bf16(q[i]) --------
__global__ void prep_kernel(const float* __restrict__ wih, const float* __restrict__ whh,
                            const float* __restrict__ kemb, const float* __restrict__ qemb,
                            const int* __restrict__ rank,
                            u16* __restrict__ wih_bf, u16* __restrict__ whh_bf,
                            u16* __restrict__ k_bf, u16* __restrict__ h0)
{
  size_t o = ((size_t)blockIdx.x * 256 + threadIdx.x) * 8;
  if (o < (size_t)H3 * H_DIM) {
    float4 a0 = *(const float4*)(wih + o), a1 = *(const float4*)(wih + o + 4);
    *(uint4*)(wih_bf + o) = make_uint4(pack2(a0.x,a0.y), pack2(a0.z,a0.w),
                                       pack2(a1.x,a1.y), pack2(a1.z,a1.w));
    float4 b0 = *(const float4*)(whh + o), b1 = *(const float4*)(whh + o + 4);
    *(uint4*)(whh_bf + o) = make_uint4(pack2(b0.x,b0.y), pack2(b0.z,b0.w),
                                       pack2(b1.x,b1.y), pack2(b1.z,b1.w));
  }
  if (o < (size_t)B_SZ * H_DIM) {
    float4 k0 = *(const float4*)(kemb + o), k1 = *(const float4*)(kemb + o + 4);
    *(uint4*)(k_bf + o) = make_uint4(pack2(k0.x,k0.y), pack2(k0.z,k0.w),
                                     pack2(k1.x,k1.y), pack2(k1.z,k1.w));
    int i = (int)(o / H_DIM), col = (int)(o % H_DIM);
    float4 q0 = *(const float4*)(qemb + o), q1 = *(const float4*)(qemb + o + 4);
    *(uint4*)(h0 + (size_t)rank[i] * H_DIM + col) =
        make_uint4(pack2(q0.x,q0.y), pack2(q0.z,q0.w),
                   pack2(q1.x,q1.y), pack2(q1.z,q1.w));
  }
}

// ------- convx: f32 -> bf16, scattered ONCE into (t, rank)-packed order -----
__global__ void convx_kernel(const float* __restrict__ x, const int* __restrict__ rowmap,
                             u16* __restrict__ xt, int total){
  size_t o = ((size_t)blockIdx.x * 256 + threadIdx.x) * 8;
  int row = (int)(o / H_DIM), col = (int)(o % H_DIM);
  if (row < total) {
    float4 a0 = *(const float4*)(x + o), a1 = *(const float4*)(x + o + 4);
    *(uint4*)(xt + (size_t)rowmap[row] * H_DIM + col) =
        make_uint4(pack2(a0.x,a0.y), pack2(a0.z,a0.w),
                   pack2(a1.x,a1.y), pack2(a1.z,a1.w));
  } else {
    *(uint4*)(xt + o) = make_uint4(0,0,0,0);   // zero padding rows
  }
}

// ---------------- GI = xt @ W_ih^T + b_ih  (256x256 tile, BK=64) ------------
// Fine-grained 8-phase schedule (T3+T4).
__global__ __launch_bounds__(512, 2) void gi_gemm_kernel(
    const u16* __restrict__ x_bf, const u16* __restrict__ wih_bf,
    const float* __restrict__ b_ih, u16* __restrict__ gi, int mt)
{
  int nblk = mt * 18;
  int id = blockIdx.x;
  int q8 = nblk >> 3, r8 = nblk & 7;
  int xcd = id & 7, off = id >> 3;
  int swz = (xcd < r8) ? (xcd * (q8 + 1) + off) : (r8 * (q8 + 1) + (xcd - r8) * q8 + off);
  int bx = swz / 18, by = swz % 18;

  __shared__ u16 lds[2 * 32768];          // 128 KB
  char* ldsb = (char*)lds;

  int tid = threadIdx.x, wid = tid >> 6, lane = tid & 63;
  int wm = wid >> 2, wn = wid & 3;        // 2m x 4n wave grid
  int lrow = lane & 15, lkh = lane >> 4;

  f32x4 acc[8][4] = {};

  auto SH = [&](int dbuf, int which, int tile){  // which: 0=Alo 1=Ahi 2=Blo 3=Bhi
    char* base = ldsb + dbuf * 65536 + which * 16384;
    int k0 = tile * 64;
    #pragma unroll
    for (int it = 0; it < 2; ++it) {
      int cb = wid * 128 + it * 64;
      int c  = cb + lane;
      int row = c >> 3, slot = c & 7;
      const u16* src;
      if (which < 2) src = x_bf   + (size_t)(bx * 256 + which * 128 + row) * H_DIM;
      else           src = wih_bf + (size_t)(by * 256 + (which - 2) * 128 + row) * H_DIM;
      src += k0 + ((slot ^ (row & 7)) << 3);
      gload_lds16(src, base + (size_t)cb * 16);
    }
  };

  SH(0,2,0); SH(0,3,0); SH(0,0,0); SH(0,1,0); SH(1,2,1); SH(1,3,1);
  asm volatile("s_waitcnt vmcnt(4)" ::: "memory");
  __builtin_amdgcn_sched_barrier(0);
  __builtin_amdgcn_s_barrier();
  __builtin_amdgcn_sched_barrier(0);

  short8 bfr[4][2], afr[2][2];

  for (int k = 0; k < 24; ++k) {
    int d = k & 1;
    char* Ab = ldsb + d * 65536 + wm * 16384;
    char* Bb = ldsb + d * 65536 + 32768 + (wn >> 1) * 16384;
    int bloc = (wn & 1) * 64;

    #pragma unroll
    for (int cf = 0; cf < 4; ++cf)
      #pragma unroll
      for (int ks = 0; ks < 2; ++ks) {
        int r = bloc + cf * 16 + lrow;
        bfr[cf][ks] = *(const short8*)(Bb + r * 128 + (((ks*4+lkh) ^ (r & 7)) << 4));
      }
    #pragma unroll
    for (int rq = 0; rq < 2; ++rq)
      #pragma unroll
      for (int ks = 0; ks < 2; ++ks) {
        int r = rq * 16 + lrow;
        afr[rq][ks] = *(const short8*)(Ab + r * 128 + (((ks*4+lkh) ^ (r & 7)) << 4));
      }
    if (k + 1 < 24) SH(d ^ 1, 0, k + 1);
    __builtin_amdgcn_s_setprio(1);
    #pragma unroll
    for (int rq = 0; rq < 2; ++rq)
      #pragma unroll
      for (int cf = 0; cf < 4; ++cf)
        #pragma unroll
        for (int ks = 0; ks < 2; ++ks)
          acc[rq][cf] = __builtin_amdgcn_mfma_f32_16x16x32_bf16(
              afr[rq][ks], bfr[cf][ks], acc[rq][cf], 0, 0, 0);
    __builtin_amdgcn_s_setprio(0);
    __builtin_amdgcn_s_barrier();
    __builtin_amdgcn_sched_barrier(0);

    #pragma unroll
    for (int q = 1; q < 4; ++q) {
      #pragma unroll
      for (int rq = 0; rq < 2; ++rq)
        #pragma unroll
        for (int ks = 0; ks < 2; ++ks) {
          int r = (q * 2 + rq) * 16 + lrow;
          afr[rq][ks] = *(const short8*)(Ab + r * 128 + (((ks*4+lkh) ^ (r & 7)) << 4));
        }
      if (q == 1) {
        if (k + 1 < 24) SH(d ^ 1, 1, k + 1);
        if (k + 2 < 24) SH(d,     2, k + 2);
      } else if (q == 2) {
        if (k + 2 < 24) SH(d,     3, k + 2);
      }
      __builtin_amdgcn_s_setprio(1);
      #pragma unroll
      for (int rq = 0; rq < 2; ++rq)
        #pragma unroll
        for (int cf = 0; cf < 4; ++cf)
          #pragma unroll
          for (int ks = 0; ks < 2; ++ks)
            acc[q*2+rq][cf] = __builtin_amdgcn_mfma_f32_16x16x32_bf16(
                afr[rq][ks], bfr[cf][ks], acc[q*2+rq][cf], 0, 0, 0);
      __builtin_amdgcn_s_setprio(0);
      if (q == 3) {
        if (k < 22) asm volatile("s_waitcnt vmcnt(4)" ::: "memory");
        else        asm volatile("s_waitcnt vmcnt(0)" ::: "memory");
        __builtin_amdgcn_sched_barrier(0);
      }
      __builtin_amdgcn_s_barrier();
      __builtin_amdgcn_sched_barrier(0);
    }
  }

  #pragma unroll
  for (int cf = 0; cf < 4; ++cf) {
    int j = by * 256 + wn * 64 + cf * 16 + lrow;
    float bias = b_ih[j];
    #pragma unroll
    for (int rf = 0; rf < 8; ++rf)
      #pragma unroll
      for (int r4 = 0; r4 < 4; ++r4) {
        int rowg = bx * 256 + wm * 128 + rf * 16 + lkh * 4 + r4;
        gi[(size_t)rowg * 4608 + j] = f2bf(acc[rf][cf][r4] + bias);
      }
  }
}

// -------- per-step GH + gates: BM=128 BN=32, 512 thr, less staged traffic ---
// 48 ct x ceil(cnt/128) bx blocks; 8 waves (4m x 2n); LDS 2 x 28 KB ->
// 2 blocks/CU (same CU coverage as BM=64@4/CU, 32% less staged bytes).
// 2-buffer counted vmcnt(4) pipeline; gi/bias reg-prefetch; hold from LDS.
__global__ __launch_bounds__(512, 4) void gh_step_kernel(
    const u16* __restrict__ h_cur, u16* __restrict__ h_nxt,
    const u16* __restrict__ whh_bf, const u16* __restrict__ gi,
    const float* __restrict__ b_hh,
    const int* __restrict__ cnt_arr, const int* __restrict__ tstart, int t)
{
  int cnt = cnt_arr[t];
  int bid = blockIdx.x;
  int x8 = bid & 7, jj = bid >> 3;
  int ct = x8 * 6 + jj % 6;             // col tile 0..47 (32 cols), XCD-pinned
  int bx = jj / 6;                      // row tile (128 rows)
  if (bx * 128 >= cnt) return;
  int ts = tstart[t];

  __shared__ u16 lds[2 * 14336];        // 2 x 28 KB: [A 16K | Wr 4K | Wz 4K | Wn 4K]
  char* ldsb = (char*)lds;

  int tid = threadIdx.x, wid = tid >> 6, lane = tid & 63;
  int wm = wid >> 1, wn = wid & 1;      // 4m x 2n wave grid
  int lrow = lane & 15, lkh = lane >> 4;
  f32x4 acc[3][2] = {};                 // [slab][m]
  float hold[2][4];

  // 1792 x 16B chunks: A 1024 (128 rows) + W 768 (3 x 32 rows); 224/wave
  auto STAGE = [&](int buf, int kt){    // 4 vmem insts per wave (last half-exec)
    int k0 = kt * 64;
    char* base = ldsb + buf * 28672;
    #pragma unroll
    for (int it = 0; it < 4; ++it) {
      int cb = wid * 224 + it * 64;     // wave-uniform chunk base
      int c  = cb + lane;
      if (it < 3 || lane < 32) {
        const u16* src;
        if (c < 1024) {                 // A: 128 h rows (dense prefix)
          int row = c >> 3, slot = c & 7;
          int ridx = bx * 128 + row; if (ridx >= cnt) ridx = cnt - 1;
          src = h_cur + (size_t)ridx * H_DIM + k0 + ((slot ^ (row & 7)) << 3);
        } else {                        // W slabs: 3 x 32 rows
          int w = c - 1024;
          int slab = w >> 8, row = (w >> 3) & 31, slot = w & 7;
          src = whh_bf + (size_t)(slab * H_DIM + ct * 32 + row) * H_DIM
                + k0 + ((slot ^ (row & 7)) << 3);
        }
        gload_lds16(src, base + (size_t)cb * 16);
      }
    }
  };

  auto COMPUTE = [&](int buf){
    char* base = ldsb + buf * 28672;
    #pragma unroll
    for (int qq = 0; qq < 2; ++qq) {
      short8 ah[2], bw[3];
      int slot = qq * 4 + lkh;
      #pragma unroll
      for (int m = 0; m < 2; ++m) {
        int row = wm * 32 + m * 16 + lrow;         // 0..127
        ah[m] = *(const short8*)(base + row * 128 + ((slot ^ (row & 7)) << 4));
      }
      {
        int row = wn * 16 + lrow;                  // W col-tile row 0..31
        int byte = row * 128 + ((slot ^ (row & 7)) << 4);
        #pragma unroll
        for (int s = 0; s < 3; ++s)
          bw[s] = *(const short8*)(base + 16384 + s * 4096 + byte);
      }
      #pragma unroll
      for (int s = 0; s < 3; ++s)
        #pragma unroll
        for (int m = 0; m < 2; ++m)
          acc[s][m] = __builtin_amdgcn_mfma_f32_16x16x32_bf16(
              ah[m], bw[s], acc[s][m], 0, 0, 0);
    }
  };

  STAGE(0, 0);                          // 4 vmem insts in flight

  // ---- prefetch gi gate values + biases into regs (retire under pipeline) --
  int lc = wn * 16 + lrow;
  int j = ct * 32 + lc;
  u16 pgir[2][4], pgiz[2][4], pgin[2][4];
  asm volatile("" ::: "memory");        // pin issue after STAGE(0)
  float bhr = b_hh[j], bhz = b_hh[H_DIM + j], bhn = b_hh[2*H_DIM + j];
  #pragma unroll
  for (int m = 0; m < 2; ++m)
    #pragma unroll
    for (int r4 = 0; r4 < 4; ++r4) {
      int lm = wm * 32 + m * 16 + lkh * 4 + r4;
      int ridx = bx * 128 + lm; if (ridx >= cnt) ridx = cnt - 1;
      size_t gr = (size_t)(ts + ridx) * 4608;
      pgir[m][r4] = __builtin_nontemporal_load(&gi[gr + j]);
      pgiz[m][r4] = __builtin_nontemporal_load(&gi[gr + H_DIM + j]);
      pgin[m][r4] = __builtin_nontemporal_load(&gi[gr + 2*H_DIM + j]);
    }
  asm volatile("" ::: "memory");        // pin issue before loop

  for (int kt = 0; kt < 24; ++kt) {
    if (kt + 1 < 24) {
      STAGE((kt + 1) & 1, kt + 1);      // 8 vmem outstanding
      asm volatile("s_waitcnt vmcnt(4)" ::: "memory");   // stage kt landed
    } else {
      asm volatile("s_waitcnt vmcnt(0)" ::: "memory");
    }
    __builtin_amdgcn_sched_barrier(0);
    __builtin_amdgcn_s_barrier();       // all waves' stage-kt loads landed
    __builtin_amdgcn_sched_barrier(0);
    COMPUTE(kt & 1);
    if (kt == (ct >> 1)) {
      // this K-chunk's A-tile holds our own h cols [ct*32, ct*32+32):
      char* base = ldsb + (kt & 1) * 28672;
      int col = ((ct & 1) << 5) + wn * 16 + lrow;   // 0..63 within K-chunk
      int slot = col >> 3, within = col & 7;
      #pragma unroll
      for (int m = 0; m < 2; ++m)
        #pragma unroll
        for (int r4 = 0; r4 < 4; ++r4) {
          int row = wm * 32 + m * 16 + lkh * 4 + r4;
          hold[m][r4] = bf2f(*(const u16*)(base + row * 128 +
                             ((slot ^ (row & 7)) << 4) + within * 2));
        }
    }
    __builtin_amdgcn_s_barrier();       // buf free before stage kt+2 overwrites
    __builtin_amdgcn_sched_barrier(0);
  }

  // gates — all inputs already in registers
  #pragma unroll
  for (int m = 0; m < 2; ++m)
    #pragma unroll
    for (int r4 = 0; r4 < 4; ++r4) {
      int lm = wm * 32 + m * 16 + lkh * 4 + r4;
      int ridx = bx * 128 + lm;
      if (ridx < cnt) {
        float rr = sigm(bf2f(pgir[m][r4]) + acc[0][m][r4] + bhr);
        float zz = sigm(bf2f(pgiz[m][r4]) + acc[1][m][r4] + bhz);
        float nn = tanhf(bf2f(pgin[m][r4]) + rr * (acc[2][m][r4] + bhn));
        h_nxt[(size_t)ridx * H_DIM + j] = f2bf((1.f - zz) * nn + zz * hold[m][r4]);
      }
    }
}

// ---------------- scores: (h_final/T) @ k^T, counted-vmcnt pipeline ---------
__global__ __launch_bounds__(256, 2) void scores_kernel(
    const u16* __restrict__ h0, const u16* __restrict__ h1,
    const int* __restrict__ lens, const int* __restrict__ rank,
    const u16* __restrict__ k_bf, float* __restrict__ scores)
{
  int bx = blockIdx.x, by = blockIdx.y;
  __shared__ u16 lds[2 * 2 * 64 * 64];   // 2 buf x (A 8K | B 8K) = 32 KB
  char* ldsb = (char*)lds;
  int tid = threadIdx.x, wid = tid >> 6, lane = tid & 63;
  int wm = wid >> 1, wn = wid & 1;
  int lrow = lane & 15, lkh = lane >> 4;
  f32x4 acc[2][2] = {};

  auto STAGE = [&](int buf, int kt){     // 4 chunks/thread
    int k0 = kt * 64;
    char* base = ldsb + buf * 16384;
    #pragma unroll
    for (int it = 0; it < 4; ++it) {
      int cb = it * 256 + wid * 64;
      int c  = cb + lane;
      int isB = c >> 9;
      int cc  = c & 511;
      int row = cc >> 3, slot = cc & 7;
      const u16* src;
      if (!isB) {
        int g = bx * 64 + row;
        src = ((lens[g] & 1) ? h1 : h0) + (size_t)rank[g] * H_DIM;
      } else {
        src = k_bf + (size_t)(by * 64 + row) * H_DIM;
      }
      src += k0 + ((slot ^ (row & 7)) << 3);
      gload_lds16(src, base + (size_t)cb * 16);
    }
  };

  auto COMPUTE = [&](int buf){
    char* base = ldsb + buf * 16384;
    #pragma unroll
    for (int qq = 0; qq < 2; ++qq) {
      short8 a[2], b[2];
      int slot = qq * 4 + lkh;
      #pragma unroll
      for (int m = 0; m < 2; ++m) {
        int row = wm * 32 + m * 16 + lrow;
        a[m] = *(const short8*)(base + row * 128 + ((slot ^ (row & 7)) << 4));
      }
      #pragma unroll
      for (int n = 0; n < 2; ++n) {
        int row = wn * 32 + n * 16 + lrow;
        b[n] = *(const short8*)(base + 8192 + row * 128 + ((slot ^ (row & 7)) << 4));
      }
      #pragma unroll
      for (int m = 0; m < 2; ++m)
        #pragma unroll
        for (int n = 0; n < 2; ++n)
          acc[m][n] = __builtin_amdgcn_mfma_f32_16x16x32_bf16(a[m], b[n], acc[m][n], 0,0,0);
    }
  };

  STAGE(0, 0);
  for (int kt = 0; kt < 24; ++kt) {
    if (kt + 1 < 24) {
      STAGE((kt + 1) & 1, kt + 1);
      asm volatile("s_waitcnt vmcnt(4)" ::: "memory");
    } else {
      asm volatile("s_waitcnt vmcnt(0)" ::: "memory");
    }
    __builtin_amdgcn_sched_barrier(0);
    __builtin_amdgcn_s_barrier();
    __builtin_amdgcn_sched_barrier(0);
    COMPUTE(kt & 1);
    __builtin_amdgcn_s_barrier();
    __builtin_amdgcn_sched_barrier(0);
  }
  #pragma unroll
  for (int m = 0; m < 2; ++m)
    #pragma unroll
    for (int n = 0; n < 2; ++n) {
      int col = by * 64 + wn * 32 + n * 16 + lrow;
      #pragma unroll
      for (int r4 = 0; r4 < 4; ++r4) {
        int rowg = bx * 64 + wm * 32 + m * 16 + lkh * 4 + r4;
        scores[(size_t)rowg * B_SZ + col] = acc[m][n][r4] * TEMP_INV;
      }
    }
}

// ------- per-row logsumexp loss, atomic accumulate into out[0] --------------
__global__ void softmax_kernel(const float* __restrict__ scores, float* __restrict__ out){
  int i = blockIdx.x;
  int tid = threadIdx.x;
  const float* row = scores + (size_t)i * B_SZ;
  __shared__ float red[4];
  float m = -INFINITY;
  for (int j = tid; j < B_SZ; j += 256) m = fmaxf(m, row[j]);
  for (int off = 32; off; off >>= 1) m = fmaxf(m, __shfl_xor(m, off));
  if ((tid & 63) == 0) red[tid >> 6] = m;
  __syncthreads();
  m = fmaxf(fmaxf(red[0], red[1]), fmaxf(red[2], red[3]));
  __syncthreads();
  float s = 0.f;
  for (int j = tid; j < B_SZ; j += 256) s += __expf(row[j] - m);
  for (int off = 32; off; off >>= 1) s += __shfl_xor(s, off);
  if ((tid & 63) == 0) red[tid >> 6] = s;
  __syncthreads();
  if (tid == 0) {
    float S = red[0] + red[1] + red[2] + red[3];
    atomicAdd(out, (m + __logf(S) - row[i]) * (1.0f / B_SZ));
  }
}

// ---------------- launch ----------------
extern "C" void kernel_launch(void* const* d_in, const int* in_sizes, int n_in,
                              void* d_out, int out_size, void* d_ws, size_t ws_size,
                              hipStream_t stream) {
  const float* q_emb = (const float*)d_in[0];
  const float* k_emb = (const float*)d_in[1];
  const float* inpn  = (const float*)d_in[2];
  const int*   lens  = (const int*)d_in[3];
  const float* wih   = (const float*)d_in[4];
  const float* whh   = (const float*)d_in[5];
  const float* bih   = (const float*)d_in[6];
  const float* bhh   = (const float*)d_in[7];
  float* out = (float*)d_out;

  int total  = in_sizes[2] / H_DIM;
  int mtiles = (total + 255) / 256;       // 256-row tiles for gi
  int Mpad   = mtiles * 256;

  char* p = (char*)d_ws;
  auto alloc = [&](size_t bytes){ char* r = p; p += (bytes + 255) & ~(size_t)255; return r; };
  int* rank      = (int*)alloc(B_SZ * 4);
  int* cnt_arr   = (int*)alloc(LMAX * 4);
  int* tstart    = (int*)alloc(LMAX * 4);
  int* rowmap    = (int*)alloc((size_t)Mpad * 4);
  u16* hbuf0     = (u16*)alloc((size_t)B_SZ * H_DIM * 2);
  u16* hbuf1     = (u16*)alloc((size_t)B_SZ * H_DIM * 2);
  u16* wih_bf    = (u16*)alloc((size_t)H3 * H_DIM * 2);
  u16* whh_bf    = (u16*)alloc((size_t)H3 * H_DIM * 2);
  u16* k_bf      = (u16*)alloc((size_t)B_SZ * H_DIM * 2);
  u16* xt        = (u16*)alloc((size_t)Mpad * H_DIM * 2);
  u16* gi        = (u16*)alloc((size_t)Mpad * H3 * 2);
  float* scores  = (float*)alloc((size_t)B_SZ * B_SZ * 4);
  if ((size_t)(p - (char*)d_ws) > ws_size) return;  // workspace too small (loud fail)

  hipMemsetAsync(out, 0, 4, stream);      // atomic accumulation target

  sort_kernel<<<1, B_SZ, 0, stream>>>(lens, rank, cnt_arr, tstart, rowmap);
  prep_kernel<<<(H3 * H_DIM / 8) / 256, 256, 0, stream>>>(
      wih, whh, k_emb, q_emb, rank, wih_bf, whh_bf, k_bf, hbuf0);
  convx_kernel<<<((size_t)Mpad * H_DIM / 8) / 256, 256, 0, stream>>>(
      inpn, rowmap, xt, total);

  gi_gemm_kernel<<<mtiles * 18, 512, 0, stream>>>(xt, wih_bf, bih, gi, mtiles);

  for (int t = 0; t < LMAX; ++t) {
    u16* hc = (t & 1) ? hbuf1 : hbuf0;
    u16* hn = (t & 1) ? hbuf0 : hbuf1;
    int cmax = total / (t + 1); if (cmax > B_SZ) cmax = B_SZ;
    if (cmax <= 0) break;
    int tiles = (cmax + 127) / 128;       // 128-row tiles now
    gh_step_kernel<<<48 * tiles, 512, 0, stream>>>(
        hc, hn, whh_bf, gi, bhh, cnt_arr, tstart, t);
  }

  scores_kernel<<<dim3(B_SZ / 64, B_SZ / 64), 256, 0, stream>>>(
      hbuf0, hbuf1, lens, rank, k_bf, scores);
  softmax_kernel<<<B_SZ, 256, 0, stream>>>(scores, out);
}

// Round 19
// 926.876 us; speedup vs baseline: 1.0944x; 1.0944x over previous
//
#include <hip/hip_runtime.h>
#include <hip/hip_bf16.h>

#define B_SZ 1024
#define H_DIM 1536
#define H3 (3*H_DIM)
#define LMAX 32
#define TEMP_INV 20.0f

typedef __attribute__((ext_vector_type(4))) float f32x4;
typedef __attribute__((ext_vector_type(8))) short short8;
typedef unsigned short u16;
typedef unsigned int u32;

__device__ __forceinline__ u16 f2bf(float f){
  union { float f; u32 u; } v; v.f = f;
  u32 r = (v.u + 0x7FFFu + ((v.u >> 16) & 1u)) >> 16;
  return (u16)r;
}
__device__ __forceinline__ u32 pack2(float lo, float hi){
  return (u32)f2bf(lo) | ((u32)f2bf(hi) << 16);
}
__device__ __forceinline__ float bf2f(u16 b){
  union { u32 u; float f; } v; v.u = ((u32)b) << 16; return v.f;
}
__device__ __forceinline__ float sigm(float x){ return 1.f / (1.f + __expf(-x)); }

__device__ __forceinline__ void gload_lds16(const void* g, void* l){
  __builtin_amdgcn_global_load_lds(
      (const __attribute__((address_space(1))) void*)g,
      (__attribute__((address_space(3))) void*)l, 16, 0, 0);
}

// ---- sort: ballot-based counting rank (desc by len, stable) ----------------
__global__ void sort_kernel(const int* __restrict__ lens, int* __restrict__ rank,
                            int* __restrict__ cnt_arr, int* __restrict__ tstart,
                            int* __restrict__ rowmap)
{
  __shared__ int wavecnt[33][17];   // [bin][wave], padded
  __shared__ int bintot[33];
  __shared__ int scnt[LMAX];
  __shared__ int sts[LMAX];
  __shared__ int soff[B_SZ];
  int i = threadIdx.x;
  int li = lens[i];
  int w = i >> 6, lane = i & 63;

  if (i < 33 * 17) ((int*)wavecnt)[i] = 0;
  __syncthreads();

  int mypre = 0;
  #pragma unroll 1
  for (int b = 0; b <= 32; ++b) {
    unsigned long long m = __ballot(li == b);
    if (lane == 0) wavecnt[b][w] = __popcll(m);
    if (b == li) mypre = __popcll(m & ((1ull << lane) - 1ull));
  }
  __syncthreads();

  if (i < 33) {
    int c = 0;
    #pragma unroll 1
    for (int w2 = 0; w2 < 16; ++w2) c += wavecnt[i][w2];
    bintot[i] = c;
  }
  __syncthreads();

  int wpre = 0;
  #pragma unroll 1
  for (int w2 = 0; w2 < w; ++w2) wpre += wavecnt[li][w2];
  int base = 0;
  #pragma unroll 1
  for (int b = li + 1; b <= 32; ++b) base += bintot[b];
  int r = base + wpre + mypre;
  rank[i] = r;

  if (i < LMAX) {
    int c = 0;
    #pragma unroll 1
    for (int b = i + 1; b <= 32; ++b) c += bintot[b];
    scnt[i] = c; cnt_arr[i] = c;
  }
  __syncthreads();
  if (i == 0) {
    int acc = 0;
    for (int t = 0; t < LMAX; ++t) { sts[t] = acc; tstart[t] = acc; acc += scnt[t]; }
  }

  soff[i] = li;
  __syncthreads();
  for (int off = 1; off < B_SZ; off <<= 1) {
    int v = (i >= off) ? soff[i - off] : 0;
    __syncthreads();
    soff[i] += v;
    __syncthreads();
  }
  int myoff = soff[i] - li;
  for (int t = 0; t < li; ++t)
    rowmap[myoff + t] = sts[t] + r;       // packed (t, rank) position
}

// ---------------- prep: weights/k -> bf16, hs0[rank[i]] = bf16(q[i]) --------
__global__ void prep_kernel(const float* __restrict__ wih, const float* __restrict__ whh,
                            const float* __restrict__ kemb, const float* __restrict__ qemb,
                            const int* __restrict__ rank,
                            u16* __restrict__ wih_bf, u16* __restrict__ whh_bf,
                            u16* __restrict__ k_bf, u16* __restrict__ h0)
{
  size_t o = ((size_t)blockIdx.x * 256 + threadIdx.x) * 8;
  if (o < (size_t)H3 * H_DIM) {
    float4 a0 = *(const float4*)(wih + o), a1 = *(const float4*)(wih + o + 4);
    *(uint4*)(wih_bf + o) = make_uint4(pack2(a0.x,a0.y), pack2(a0.z,a0.w),
                                       pack2(a1.x,a1.y), pack2(a1.z,a1.w));
    float4 b0 = *(const float4*)(whh + o), b1 = *(const float4*)(whh + o + 4);
    *(uint4*)(whh_bf + o) = make_uint4(pack2(b0.x,b0.y), pack2(b0.z,b0.w),
                                       pack2(b1.x,b1.y), pack2(b1.z,b1.w));
  }
  if (o < (size_t)B_SZ * H_DIM) {
    float4 k0 = *(const float4*)(kemb + o), k1 = *(const float4*)(kemb + o + 4);
    *(uint4*)(k_bf + o) = make_uint4(pack2(k0.x,k0.y), pack2(k0.z,k0.w),
                                     pack2(k1.x,k1.y), pack2(k1.z,k1.w));
    int i = (int)(o / H_DIM), col = (int)(o % H_DIM);
    float4 q0 = *(const float4*)(qemb + o), q1 = *(const float4*)(qemb + o + 4);
    *(uint4*)(h0 + (size_t)rank[i] * H_DIM + col) =
        make_uint4(pack2(q0.x,q0.y), pack2(q0.z,q0.w),
                   pack2(q1.x,q1.y), pack2(q1.z,q1.w));
  }
}

// ------- convx: f32 -> bf16, scattered ONCE into (t, rank)-packed order -----
__global__ void convx_kernel(const float* __restrict__ x, const int* __restrict__ rowmap,
                             u16* __restrict__ xt, int total){
  size_t o = ((size_t)blockIdx.x * 256 + threadIdx.x) * 8;
  int row = (int)(o / H_DIM), col = (int)(o % H_DIM);
  if (row < total) {
    float4 a0 = *(const float4*)(x + o), a1 = *(const float4*)(x + o + 4);
    *(uint4*)(xt + (size_t)rowmap[row] * H_DIM + col) =
        make_uint4(pack2(a0.x,a0.y), pack2(a0.z,a0.w),
                   pack2(a1.x,a1.y), pack2(a1.z,a1.w));
  } else {
    *(uint4*)(xt + o) = make_uint4(0,0,0,0);   // zero padding rows
  }
}

// ---------------- GI = xt @ W_ih^T + b_ih  (256x256 tile, BK=64) ------------
// Fine-grained 8-phase schedule (T3+T4): per K-tile 4 phases, each
// {ds_read frags || stage 1 half-tile || 16 MFMA (setprio)} + ONE barrier;
// vmcnt(4) once per K-tile (never 0 until last 2 tiles).
__global__ __launch_bounds__(512, 2) void gi_gemm_kernel(
    const u16* __restrict__ x_bf, const u16* __restrict__ wih_bf,
    const float* __restrict__ b_ih, u16* __restrict__ gi, int mt)
{
  int nblk = mt * 18;
  int id = blockIdx.x;
  int q8 = nblk >> 3, r8 = nblk & 7;
  int xcd = id & 7, off = id >> 3;
  int swz = (xcd < r8) ? (xcd * (q8 + 1) + off) : (r8 * (q8 + 1) + (xcd - r8) * q8 + off);
  int bx = swz / 18, by = swz % 18;

  __shared__ u16 lds[2 * 32768];          // 128 KB
  char* ldsb = (char*)lds;

  int tid = threadIdx.x, wid = tid >> 6, lane = tid & 63;
  int wm = wid >> 2, wn = wid & 3;        // 2m x 4n wave grid
  int lrow = lane & 15, lkh = lane >> 4;

  f32x4 acc[8][4] = {};

  auto SH = [&](int dbuf, int which, int tile){  // which: 0=Alo 1=Ahi 2=Blo 3=Bhi
    char* base = ldsb + dbuf * 65536 + which * 16384;
    int k0 = tile * 64;
    #pragma unroll
    for (int it = 0; it < 2; ++it) {
      int cb = wid * 128 + it * 64;
      int c  = cb + lane;
      int row = c >> 3, slot = c & 7;
      const u16* src;
      if (which < 2) src = x_bf   + (size_t)(bx * 256 + which * 128 + row) * H_DIM;
      else           src = wih_bf + (size_t)(by * 256 + (which - 2) * 128 + row) * H_DIM;
      src += k0 + ((slot ^ (row & 7)) << 3);
      gload_lds16(src, base + (size_t)cb * 16);
    }
  };

  SH(0,2,0); SH(0,3,0); SH(0,0,0); SH(0,1,0); SH(1,2,1); SH(1,3,1);
  asm volatile("s_waitcnt vmcnt(4)" ::: "memory");
  __builtin_amdgcn_sched_barrier(0);
  __builtin_amdgcn_s_barrier();
  __builtin_amdgcn_sched_barrier(0);

  short8 bfr[4][2], afr[2][2];

  for (int k = 0; k < 24; ++k) {
    int d = k & 1;
    char* Ab = ldsb + d * 65536 + wm * 16384;
    char* Bb = ldsb + d * 65536 + 32768 + (wn >> 1) * 16384;
    int bloc = (wn & 1) * 64;

    #pragma unroll
    for (int cf = 0; cf < 4; ++cf)
      #pragma unroll
      for (int ks = 0; ks < 2; ++ks) {
        int r = bloc + cf * 16 + lrow;
        bfr[cf][ks] = *(const short8*)(Bb + r * 128 + (((ks*4+lkh) ^ (r & 7)) << 4));
      }
    #pragma unroll
    for (int rq = 0; rq < 2; ++rq)
      #pragma unroll
      for (int ks = 0; ks < 2; ++ks) {
        int r = rq * 16 + lrow;
        afr[rq][ks] = *(const short8*)(Ab + r * 128 + (((ks*4+lkh) ^ (r & 7)) << 4));
      }
    if (k + 1 < 24) SH(d ^ 1, 0, k + 1);
    __builtin_amdgcn_s_setprio(1);
    #pragma unroll
    for (int rq = 0; rq < 2; ++rq)
      #pragma unroll
      for (int cf = 0; cf < 4; ++cf)
        #pragma unroll
        for (int ks = 0; ks < 2; ++ks)
          acc[rq][cf] = __builtin_amdgcn_mfma_f32_16x16x32_bf16(
              afr[rq][ks], bfr[cf][ks], acc[rq][cf], 0, 0, 0);
    __builtin_amdgcn_s_setprio(0);
    __builtin_amdgcn_s_barrier();
    __builtin_amdgcn_sched_barrier(0);

    #pragma unroll
    for (int q = 1; q < 4; ++q) {
      #pragma unroll
      for (int rq = 0; rq < 2; ++rq)
        #pragma unroll
        for (int ks = 0; ks < 2; ++ks) {
          int r = (q * 2 + rq) * 16 + lrow;
          afr[rq][ks] = *(const short8*)(Ab + r * 128 + (((ks*4+lkh) ^ (r & 7)) << 4));
        }
      if (q == 1) {
        if (k + 1 < 24) SH(d ^ 1, 1, k + 1);
        if (k + 2 < 24) SH(d,     2, k + 2);
      } else if (q == 2) {
        if (k + 2 < 24) SH(d,     3, k + 2);
      }
      __builtin_amdgcn_s_setprio(1);
      #pragma unroll
      for (int rq = 0; rq < 2; ++rq)
        #pragma unroll
        for (int cf = 0; cf < 4; ++cf)
          #pragma unroll
          for (int ks = 0; ks < 2; ++ks)
            acc[q*2+rq][cf] = __builtin_amdgcn_mfma_f32_16x16x32_bf16(
                afr[rq][ks], bfr[cf][ks], acc[q*2+rq][cf], 0, 0, 0);
      __builtin_amdgcn_s_setprio(0);
      if (q == 3) {
        if (k < 22) asm volatile("s_waitcnt vmcnt(4)" ::: "memory");
        else        asm volatile("s_waitcnt vmcnt(0)" ::: "memory");
        __builtin_amdgcn_sched_barrier(0);
      }
      __builtin_amdgcn_s_barrier();
      __builtin_amdgcn_sched_barrier(0);
    }
  }

  #pragma unroll
  for (int cf = 0; cf < 4; ++cf) {
    int j = by * 256 + wn * 64 + cf * 16 + lrow;
    float bias = b_ih[j];
    #pragma unroll
    for (int rf = 0; rf < 8; ++rf)
      #pragma unroll
      for (int r4 = 0; r4 < 4; ++r4) {
        int rowg = bx * 256 + wm * 128 + rf * 16 + lkh * 4 + r4;
        gi[(size_t)rowg * 4608 + j] = f2bf(acc[rf][cf][r4] + bias);
      }
  }
}

// -------- per-step GH + gates: BM=64 BN=32, grid-capped, gi reg-prefetch ----
__global__ __launch_bounds__(256, 4) void gh_step_kernel(
    const u16* __restrict__ h_cur, u16* __restrict__ h_nxt,
    const u16* __restrict__ whh_bf, const u16* __restrict__ gi,
    const float* __restrict__ b_hh,
    const int* __restrict__ cnt_arr, const int* __restrict__ tstart, int t)
{
  int cnt = cnt_arr[t];
  int bid = blockIdx.x;
  int x8 = bid & 7, jj = bid >> 3;
  int ct = x8 * 6 + jj % 6;             // col tile 0..47 (32 cols), XCD-pinned
  int bx = jj / 6;                      // row tile (64 rows)
  if (bx * 64 >= cnt) return;
  int ts = tstart[t];

  __shared__ u16 lds[2 * 10240];        // 2 x 20 KB: [A 8K | Wr 4K | Wz 4K | Wn 4K]
  char* ldsb = (char*)lds;

  int tid = threadIdx.x, wid = tid >> 6, lane = tid & 63;
  int wm = wid >> 1, wn = wid & 1;      // 2m x 2n wave grid
  int lrow = lane & 15, lkh = lane >> 4;
  f32x4 acc[3][2] = {};
  float hold[2][4];

  auto STAGE = [&](int buf, int kt){    // 5 chunks per thread (1280 x 16B)
    int k0 = kt * 64;
    char* base = ldsb + buf * 20480;
    #pragma unroll
    for (int it = 0; it < 5; ++it) {
      int cb = it * 256 + wid * 64;     // wave-uniform chunk base
      int c  = cb + lane;
      const u16* src;
      if (c < 512) {                    // A: 64 h rows (dense prefix)
        int row = c >> 3, slot = c & 7;
        int ridx = bx * 64 + row; if (ridx >= cnt) ridx = cnt - 1;
        src = h_cur + (size_t)ridx * H_DIM + k0 + ((slot ^ (row & 7)) << 3);
      } else {                          // W slabs: 3 x 32 rows
        int w = c - 512;
        int slab = w >> 8, row = (w >> 3) & 31, slot = w & 7;
        src = whh_bf + (size_t)(slab * H_DIM + ct * 32 + row) * H_DIM
              + k0 + ((slot ^ (row & 7)) << 3);
      }
      gload_lds16(src, base + (size_t)cb * 16);
    }
  };

  auto COMPUTE = [&](int buf){
    char* base = ldsb + buf * 20480;
    #pragma unroll
    for (int qq = 0; qq < 2; ++qq) {
      short8 ah[2], bw[3];
      int slot = qq * 4 + lkh;
      #pragma unroll
      for (int m = 0; m < 2; ++m) {
        int row = wm * 32 + m * 16 + lrow;
        ah[m] = *(const short8*)(base + row * 128 + ((slot ^ (row & 7)) << 4));
      }
      {
        int row = wn * 16 + lrow;       // W col-tile row 0..31
        int byte = row * 128 + ((slot ^ (row & 7)) << 4);
        #pragma unroll
        for (int s = 0; s < 3; ++s)
          bw[s] = *(const short8*)(base + 8192 + s * 4096 + byte);
      }
      #pragma unroll
      for (int s = 0; s < 3; ++s)
        #pragma unroll
        for (int m = 0; m < 2; ++m)
          acc[s][m] = __builtin_amdgcn_mfma_f32_16x16x32_bf16(
              ah[m], bw[s], acc[s][m], 0, 0, 0);
    }
  };

  STAGE(0, 0);                          // 5 loads in flight

  // ---- prefetch gi gate values + biases into regs (retire under pipeline) --
  int lc = wn * 16 + lrow;
  int j = ct * 32 + lc;
  u16 pgir[2][4], pgiz[2][4], pgin[2][4];
  asm volatile("" ::: "memory");        // pin issue after STAGE(0)
  float bhr = b_hh[j], bhz = b_hh[H_DIM + j], bhn = b_hh[2*H_DIM + j];
  #pragma unroll
  for (int m = 0; m < 2; ++m)
    #pragma unroll
    for (int r4 = 0; r4 < 4; ++r4) {
      int lm = wm * 32 + m * 16 + lkh * 4 + r4;
      int ridx = bx * 64 + lm; if (ridx >= cnt) ridx = cnt - 1;
      size_t gr = (size_t)(ts + ridx) * 4608;
      pgir[m][r4] = __builtin_nontemporal_load(&gi[gr + j]);
      pgiz[m][r4] = __builtin_nontemporal_load(&gi[gr + H_DIM + j]);
      pgin[m][r4] = __builtin_nontemporal_load(&gi[gr + 2*H_DIM + j]);
    }
  asm volatile("" ::: "memory");        // pin issue before loop

  for (int kt = 0; kt < 24; ++kt) {
    if (kt + 1 < 24) {
      STAGE((kt + 1) & 1, kt + 1);
      asm volatile("s_waitcnt vmcnt(5)" ::: "memory");
    } else {
      asm volatile("s_waitcnt vmcnt(0)" ::: "memory");
    }
    __builtin_amdgcn_sched_barrier(0);
    __builtin_amdgcn_s_barrier();       // all waves' stage-kt loads landed
    __builtin_amdgcn_sched_barrier(0);
    COMPUTE(kt & 1);
    if (kt == (ct >> 1)) {
      char* base = ldsb + (kt & 1) * 20480;
      int col = ((ct & 1) << 5) + wn * 16 + lrow;   // 0..63 within K-chunk
      int slot = col >> 3, within = col & 7;
      #pragma unroll
      for (int m = 0; m < 2; ++m)
        #pragma unroll
        for (int r4 = 0; r4 < 4; ++r4) {
          int row = wm * 32 + m * 16 + lkh * 4 + r4;
          hold[m][r4] = bf2f(*(const u16*)(base + row * 128 +
                             ((slot ^ (row & 7)) << 4) + within * 2));
        }
    }
    __builtin_amdgcn_s_barrier();       // buf free before stage kt+2 overwrites
    __builtin_amdgcn_sched_barrier(0);
  }

  // gates — all inputs already in registers
  #pragma unroll
  for (int m = 0; m < 2; ++m)
    #pragma unroll
    for (int r4 = 0; r4 < 4; ++r4) {
      int lm = wm * 32 + m * 16 + lkh * 4 + r4;
      int ridx = bx * 64 + lm;
      if (ridx < cnt) {
        float rr = sigm(bf2f(pgir[m][r4]) + acc[0][m][r4] + bhr);
        float zz = sigm(bf2f(pgiz[m][r4]) + acc[1][m][r4] + bhz);
        float nn = tanhf(bf2f(pgin[m][r4]) + rr * (acc[2][m][r4] + bhn));
        h_nxt[(size_t)ridx * H_DIM + j] = f2bf((1.f - zz) * nn + zz * hold[m][r4]);
      }
    }
}

// ---------------- scores: (h_final/T) @ k^T, counted-vmcnt pipeline ---------
__global__ __launch_bounds__(256, 2) void scores_kernel(
    const u16* __restrict__ h0, const u16* __restrict__ h1,
    const int* __restrict__ lens, const int* __restrict__ rank,
    const u16* __restrict__ k_bf, float* __restrict__ scores)
{
  int bx = blockIdx.x, by = blockIdx.y;
  __shared__ u16 lds[2 * 2 * 64 * 64];   // 2 buf x (A 8K | B 8K) = 32 KB
  char* ldsb = (char*)lds;
  int tid = threadIdx.x, wid = tid >> 6, lane = tid & 63;
  int wm = wid >> 1, wn = wid & 1;
  int lrow = lane & 15, lkh = lane >> 4;
  f32x4 acc[2][2] = {};

  auto STAGE = [&](int buf, int kt){     // 4 chunks/thread
    int k0 = kt * 64;
    char* base = ldsb + buf * 16384;
    #pragma unroll
    for (int it = 0; it < 4; ++it) {
      int cb = it * 256 + wid * 64;
      int c  = cb + lane;
      int isB = c >> 9;
      int cc  = c & 511;
      int row = cc >> 3, slot = cc & 7;
      const u16* src;
      if (!isB) {
        int g = bx * 64 + row;
        src = ((lens[g] & 1) ? h1 : h0) + (size_t)rank[g] * H_DIM;
      } else {
        src = k_bf + (size_t)(by * 64 + row) * H_DIM;
      }
      src += k0 + ((slot ^ (row & 7)) << 3);
      gload_lds16(src, base + (size_t)cb * 16);
    }
  };

  auto COMPUTE = [&](int buf){
    char* base = ldsb + buf * 16384;
    #pragma unroll
    for (int qq = 0; qq < 2; ++qq) {
      short8 a[2], b[2];
      int slot = qq * 4 + lkh;
      #pragma unroll
      for (int m = 0; m < 2; ++m) {
        int row = wm * 32 + m * 16 + lrow;
        a[m] = *(const short8*)(base + row * 128 + ((slot ^ (row & 7)) << 4));
      }
      #pragma unroll
      for (int n = 0; n < 2; ++n) {
        int row = wn * 32 + n * 16 + lrow;
        b[n] = *(const short8*)(base + 8192 + row * 128 + ((slot ^ (row & 7)) << 4));
      }
      #pragma unroll
      for (int m = 0; m < 2; ++m)
        #pragma unroll
        for (int n = 0; n < 2; ++n)
          acc[m][n] = __builtin_amdgcn_mfma_f32_16x16x32_bf16(a[m], b[n], acc[m][n], 0,0,0);
    }
  };

  STAGE(0, 0);
  for (int kt = 0; kt < 24; ++kt) {
    if (kt + 1 < 24) {
      STAGE((kt + 1) & 1, kt + 1);
      asm volatile("s_waitcnt vmcnt(4)" ::: "memory");
    } else {
      asm volatile("s_waitcnt vmcnt(0)" ::: "memory");
    }
    __builtin_amdgcn_sched_barrier(0);
    __builtin_amdgcn_s_barrier();
    __builtin_amdgcn_sched_barrier(0);
    COMPUTE(kt & 1);
    __builtin_amdgcn_s_barrier();
    __builtin_amdgcn_sched_barrier(0);
  }
  #pragma unroll
  for (int m = 0; m < 2; ++m)
    #pragma unroll
    for (int n = 0; n < 2; ++n) {
      int col = by * 64 + wn * 32 + n * 16 + lrow;
      #pragma unroll
      for (int r4 = 0; r4 < 4; ++r4) {
        int rowg = bx * 64 + wm * 32 + m * 16 + lkh * 4 + r4;
        scores[(size_t)rowg * B_SZ + col] = acc[m][n][r4] * TEMP_INV;
      }
    }
}

// ------- per-row logsumexp loss, atomic accumulate into out[0] --------------
__global__ void softmax_kernel(const float* __restrict__ scores, float* __restrict__ out){
  int i = blockIdx.x;
  int tid = threadIdx.x;
  const float* row = scores + (size_t)i * B_SZ;
  __shared__ float red[4];
  float m = -INFINITY;
  for (int j = tid; j < B_SZ; j += 256) m = fmaxf(m, row[j]);
  for (int off = 32; off; off >>= 1) m = fmaxf(m, __shfl_xor(m, off));
  if ((tid & 63) == 0) red[tid >> 6] = m;
  __syncthreads();
  m = fmaxf(fmaxf(red[0], red[1]), fmaxf(red[2], red[3]));
  __syncthreads();
  float s = 0.f;
  for (int j = tid; j < B_SZ; j += 256) s += __expf(row[j] - m);
  for (int off = 32; off; off >>= 1) s += __shfl_xor(s, off);
  if ((tid & 63) == 0) red[tid >> 6] = s;
  __syncthreads();
  if (tid == 0) {
    float S = red[0] + red[1] + red[2] + red[3];
    atomicAdd(out, (m + __logf(S) - row[i]) * (1.0f / B_SZ));
  }
}

// ---------------- launch ----------------
extern "C" void kernel_launch(void* const* d_in, const int* in_sizes, int n_in,
                              void* d_out, int out_size, void* d_ws, size_t ws_size,
                              hipStream_t stream) {
  const float* q_emb = (const float*)d_in[0];
  const float* k_emb = (const float*)d_in[1];
  const float* inpn  = (const float*)d_in[2];
  const int*   lens  = (const int*)d_in[3];
  const float* wih   = (const float*)d_in[4];
  const float* whh   = (const float*)d_in[5];
  const float* bih   = (const float*)d_in[6];
  const float* bhh   = (const float*)d_in[7];
  float* out = (float*)d_out;

  int total  = in_sizes[2] / H_DIM;
  int mtiles = (total + 255) / 256;       // 256-row tiles for gi
  int Mpad   = mtiles * 256;

  char* p = (char*)d_ws;
  auto alloc = [&](size_t bytes){ char* r = p; p += (bytes + 255) & ~(size_t)255; return r; };
  int* rank      = (int*)alloc(B_SZ * 4);
  int* cnt_arr   = (int*)alloc(LMAX * 4);
  int* tstart    = (int*)alloc(LMAX * 4);
  int* rowmap    = (int*)alloc((size_t)Mpad * 4);
  u16* hbuf0     = (u16*)alloc((size_t)B_SZ * H_DIM * 2);
  u16* hbuf1     = (u16*)alloc((size_t)B_SZ * H_DIM * 2);
  u16* wih_bf    = (u16*)alloc((size_t)H3 * H_DIM * 2);
  u16* whh_bf    = (u16*)alloc((size_t)H3 * H_DIM * 2);
  u16* k_bf      = (u16*)alloc((size_t)B_SZ * H_DIM * 2);
  u16* xt        = (u16*)alloc((size_t)Mpad * H_DIM * 2);
  u16* gi        = (u16*)alloc((size_t)Mpad * H3 * 2);
  float* scores  = (float*)alloc((size_t)B_SZ * B_SZ * 4);
  if ((size_t)(p - (char*)d_ws) > ws_size) return;  // workspace too small (loud fail)

  hipMemsetAsync(out, 0, 4, stream);      // atomic accumulation target

  sort_kernel<<<1, B_SZ, 0, stream>>>(lens, rank, cnt_arr, tstart, rowmap);
  prep_kernel<<<(H3 * H_DIM / 8) / 256, 256, 0, stream>>>(
      wih, whh, k_emb, q_emb, rank, wih_bf, whh_bf, k_bf, hbuf0);
  convx_kernel<<<((size_t)Mpad * H_DIM / 8) / 256, 256, 0, stream>>>(
      inpn, rowmap, xt, total);

  gi_gemm_kernel<<<mtiles * 18, 512, 0, stream>>>(xt, wih_bf, bih, gi, mtiles);

  for (int t = 0; t < LMAX; ++t) {
    u16* hc = (t & 1) ? hbuf1 : hbuf0;
    u16* hn = (t & 1) ? hbuf0 : hbuf1;
    int cmax = total / (t + 1); if (cmax > B_SZ) cmax = B_SZ;
    if (cmax <= 0) break;
    int tiles = (cmax + 63) / 64;
    gh_step_kernel<<<48 * tiles, 256, 0, stream>>>(
        hc, hn, whh_bf, gi, bhh, cnt_arr, tstart, t);
  }

  scores_kernel<<<dim3(B_SZ / 64, B_SZ / 64), 256, 0, stream>>>(
      hbuf0, hbuf1, lens, rank, k_bf, scores);
  softmax_kernel<<<B_SZ, 256, 0, stream>>>(scores, out);
}